// Round 1
// baseline (3429.701 us; speedup 1.0000x reference)
//
#include <hip/hip_runtime.h>
#include <hip/hip_bf16.h>

typedef _Float16 half2v __attribute__((ext_vector_type(2)));
typedef _Float16 half8v __attribute__((ext_vector_type(8)));
typedef float float4v __attribute__((ext_vector_type(4)));
typedef unsigned int u32;
typedef unsigned short u16;

#define DEV static __device__ __forceinline__

DEV u32 pack2(float a, float b) {
  half2v h = { (_Float16)a, (_Float16)b };
  return __builtin_bit_cast(u32, h);
}
DEV half2v uph(u32 u) { return __builtin_bit_cast(half2v, u); }
DEV u16 ftoh16(float f) { return __builtin_bit_cast(u16, (_Float16)f); }
DEV float h16tof(u16 s) { return (float)__builtin_bit_cast(_Float16, s); }

#if __has_builtin(__builtin_amdgcn_fdot2)
DEV float fdot2(half2v a, half2v b, float c) { return __builtin_amdgcn_fdot2(a, b, c, false); }
#else
DEV float fdot2(half2v a, half2v b, float c) {
  return c + (float)a.x * (float)b.x + (float)a.y * (float)b.y;
}
#endif

DEV float fast_rcp(float x) { return __builtin_amdgcn_rcpf(x); }
DEV float sigmoid_f(float x) { return fast_rcp(1.f + exp2f(-1.4426950408889634f * x)); }
DEV float tanh_f(float x) {
  float e = exp2f(x * 2.8853900817779268f);  // e^(2x)
  return 1.f - 2.f * fast_rcp(e + 1.f);
}

// Raw barrier: LDS-publish only. Deliberately NO vmcnt(0) — in-flight global
// loads/stores keep flying across it (the compiler's own data-dep vmcnt(N)
// drains them right before their LDS write, 2-3 steps after issue).
DEV void barrier_lgkm() {
  __asm__ __volatile__("s_waitcnt lgkmcnt(0)\ns_barrier" ::: "memory");
}

// ---------------------------------------------------------------------------
// Prep: transpose + f16-convert the three weight matrices (dst[c][r] = src[r][c])
// ---------------------------------------------------------------------------
__global__ void prep_transpose(const float* __restrict__ Wz, const float* __restrict__ Wh,
                               const float* __restrict__ Wo, _Float16* __restrict__ Wzt,
                               _Float16* __restrict__ Wht, _Float16* __restrict__ Wot)
{
  const float* src; _Float16* dst; int R, C;
  if (blockIdx.y == 0)      { src = Wz; dst = Wzt; R = 128; C = 256; }
  else if (blockIdx.y == 1) { src = Wh; dst = Wht; R = 128; C = 256; }
  else                      { src = Wo; dst = Wot; R = 256; C = 128; }
  int total = R * C;
  for (int idx = blockIdx.x * blockDim.x + threadIdx.x; idx < total;
       idx += gridDim.x * blockDim.x) {
    int rr = idx / C, cc = idx % C;
    dst[(size_t)cc * R + rr] = (_Float16)src[idx];
  }
}

// ---------------------------------------------------------------------------
// MFMA GEMM: out[M x N] = A[M x K] * Bt^T (+bias). Bt is [N][K] f16 (pre-transposed).
// ---------------------------------------------------------------------------
template <int K, int N, bool A_F32, bool OUT_F16>
__global__ __launch_bounds__(256, 2) void gemm_mfma(
    const void* __restrict__ A_, const _Float16* __restrict__ Bt,
    const float* __restrict__ bias, void* __restrict__ out)
{
  __shared__ _Float16 Blds[N * K];  // 64 KB

  const int tid = threadIdx.x;
  constexpr int CHUNKS = K / 8;
  constexpr int ITER = (N * K / 8) / 256;
#pragma unroll
  for (int i = 0; i < ITER; ++i) {
    int idx = tid + i * 256;
    int n = idx / CHUNKS;
    int c = idx % CHUNKS;
    int cs = c ^ (n & 7);
    *(uint4*)(Blds + (size_t)n * K + cs * 8) =
        *(const uint4*)(Bt + (size_t)n * K + c * 8);
  }
  __syncthreads();

  const int w = tid >> 6, l = tid & 63;
  const int lm = l & 15, lq = l >> 4;
  const size_t m0 = (size_t)blockIdx.x * 128;

  float4v acc[2][N / 16] = {};

#pragma unroll
  for (int kk = 0; kk < K / 32; ++kk) {
    const int kbase = kk * 32 + lq * 8;
    half8v af[2];
#pragma unroll
    for (int ms = 0; ms < 2; ++ms) {
      const size_t row = m0 + (size_t)(w * 2 + ms) * 16 + lm;
      if constexpr (A_F32) {
        const float* ap = (const float*)A_ + row * K + kbase;
        float4 x0 = *(const float4*)ap;
        float4 x1 = *(const float4*)(ap + 4);
        af[ms] = half8v{(_Float16)x0.x, (_Float16)x0.y, (_Float16)x0.z, (_Float16)x0.w,
                        (_Float16)x1.x, (_Float16)x1.y, (_Float16)x1.z, (_Float16)x1.w};
      } else {
        af[ms] = *(const half8v*)((const _Float16*)A_ + row * K + kbase);
      }
    }
    const int c = kk * 4 + lq;
#pragma unroll
    for (int nt = 0; nt < N / 16; ++nt) {
      const int n = nt * 16 + lm;
      half8v bf = *(const half8v*)(Blds + (size_t)n * K + (c ^ (lm & 7)) * 8);
      acc[0][nt] = __builtin_amdgcn_mfma_f32_16x16x32_f16(af[0], bf, acc[0][nt], 0, 0, 0);
      acc[1][nt] = __builtin_amdgcn_mfma_f32_16x16x32_f16(af[1], bf, acc[1][nt], 0, 0, 0);
    }
  }

#pragma unroll
  for (int ms = 0; ms < 2; ++ms) {
    const size_t rowbase = m0 + (size_t)(w * 2 + ms) * 16 + lq * 4;
#pragma unroll
    for (int nt = 0; nt < N / 16; ++nt) {
      const int col = nt * 16 + lm;
      const float bcol = bias[col];
#pragma unroll
      for (int rr = 0; rr < 4; ++rr) {
        const size_t row = rowbase + rr;
        float v = acc[ms][nt][rr] + bcol;
        if constexpr (OUT_F16) ((_Float16*)out)[row * N + col] = (_Float16)v;
        else                   ((float*)out)[row * N + col] = v;
      }
    }
  }
}

// ---------------------------------------------------------------------------
// Sequential scan. One WG (512 thr, 8 waves) per batch element.
//  g0 (waves 0-3): candidate gate. 1 column/lane, full K=256 per lane.
//    a-vector = zh ring (z_t (.) h_{t-1}, precomputed) -> inner loop is
//    32 broadcast ds_read_b128 + 128 fdot2, ZERO bank conflicts, no shfl.
//  g1 (waves 4-7): z gate via MFMA once per 4 steps (u==3); all global
//    traffic issued at u==0 into REGISTERS, ds_written to LDS at u==2 so the
//    vmcnt wait lands ~2 steps (~1000cy) after issue and stays off the B3
//    path. Raw lgkm-only barriers keep HBM latency off the barrier path.
//  z-burst epilogue: the A-frag row pattern (l&3) makes all 4 lane-quads of
//  the C frag hold IDENTICAL 4x64 z-pre rows (row = reg mod 4), so quad q
//  handles time-row q: 4 sigmoids/lane wave-uniform (8 trans ops) instead of
//  16/lane under an l<16 mask (32 trans ops) — trans issue is exec-mask
//  independent, so this shortens the B3 critical path ~170cy.
//  Barriers: 5 per 4-step group (B0..B3 + mini-barrier B4 that publishes the
//  group-boundary zh after g1's z burst lands).
// ---------------------------------------------------------------------------
__global__ __launch_bounds__(512, 2) void scan_kernel(
    const u32* __restrict__ xz32, const u32* __restrict__ xh32,
    const float* __restrict__ Uz, const float* __restrict__ Uh,
    u32* __restrict__ hsOut)
{
  const int b   = blockIdx.x;
  const int tid = threadIdx.x;
  const int w   = tid >> 6;
  const int l   = tid & 63;
  const int g   = w >> 2;
  const int wv  = w & 3;

  // pitch 264 u16 (=528B): ring slots are 4 banks apart -> the 4-row MFMA
  // A-frag reads hit disjoint bank quads.
  __shared__ __align__(16) u16 histS[8][264];   // h_t, f16, 1 col per u16
  __shared__ __align__(16) u16 zringS[8][264];  // z_t
  __shared__ __align__(16) u16 zhS[8][264];     // z_t * h_{t-1}  (a-vector)
  __shared__ __align__(16) u16 xhS[2][1024];    // xh staging, 4 rows x 256
  __shared__ __align__(16) u16 xzS[2][1024];    // xz staging, 4 rows x 256

  uint4 W[32];  // overlay: g0 = Uh column c packs; g1 = Uz B-frags

  const size_t xb32 = (size_t)b * 4096 * 128;   // u32 units
  const u16* xz16v = (const u16*)xz32;
  const int c   = wv * 64 + l;        // g0: owned column / g1: linear id
  const int rr  = c >> 6;             // staging row 0..3
  const int c4  = (c & 63) * 4;       // staging col (u16), 4 per thread

  if (g == 0) {
    // Uh column c -> 128 packed f16 row-pairs (coalesced across lanes)
    const float* Ub = Uh + c;
#pragma unroll
    for (int i = 0; i < 32; ++i) {
      u32 q[4];
#pragma unroll
      for (int p2 = 0; p2 < 4; ++p2) {
        int k0 = i * 8 + p2 * 2;
        q[p2] = pack2(Ub[(size_t)k0 * 256], Ub[(size_t)(k0 + 1) * 256]);
      }
      W[i] = make_uint4(q[0], q[1], q[2], q[3]);
    }
  } else {
    // Uz -> B-fragments: W[kt*4+nt], B[k=kt*32+(l>>4)*8+j][n=wv*64+nt*16+(l&15)]
    const int lm = l & 15, lo = (l >> 4) * 8;
#pragma unroll
    for (int kt = 0; kt < 8; ++kt)
#pragma unroll
      for (int nt = 0; nt < 4; ++nt) {
        u32 q[4];
#pragma unroll
        for (int p2 = 0; p2 < 4; ++p2) {
          int k0 = kt * 32 + lo + 2 * p2;
          int cn = wv * 64 + nt * 16 + lm;
          q[p2] = pack2(Uz[(size_t)k0 * 256 + cn], Uz[(size_t)(k0 + 1) * 256 + cn]);
        }
        W[kt * 4 + nt] = make_uint4(q[0], q[1], q[2], q[3]);
      }
  }

  // zero h_{-4..-1} (slots 4..7) and zh_0 (= z_0 * h_{-1} = 0)
  for (int i = tid; i < 4 * 264; i += 512) (&histS[4][0])[i] = 0;
  for (int i = tid; i < 264; i += 512) zhS[0][i] = 0;

  if (g == 1) {
    // z_0..3 = sigmoid(xz rows 0..3);  stage xh rows 0..3, xz rows 4..7
    uint2 xzv = *(const uint2*)&xz16v[((size_t)b * 4096 + rr) * 256 + c4];
    half2v a0 = uph(xzv.x), a1 = uph(xzv.y);
    u32 z01 = pack2(sigmoid_f((float)a0.x), sigmoid_f((float)a0.y));
    u32 z23 = pack2(sigmoid_f((float)a1.x), sigmoid_f((float)a1.y));
    *(uint2*)&zringS[rr][c4] = make_uint2(z01, z23);
    *(uint2*)&xhS[0][rr * 256 + c4] =
        *(const uint2*)&xh32[xb32 + (size_t)rr * 128 + (c & 63) * 2];
    *(uint2*)&xzS[0][rr * 256 + c4] =
        *(const uint2*)&xz16v[((size_t)b * 4096 + 4 + rr) * 256 + c4];
  }
  float h = 0.f;
  __syncthreads();

  for (int tb = 0; tb < 4096; tb += 4) {
    const int p = (tb >> 2) & 1;
    uint2 xhv, xzv2;                      // g1: staged in regs u0 -> u2
#pragma unroll
    for (int u = 0; u < 4; ++u) {
      const int t = tb + u;
      if (g == 0) {
        // ---------------- candidate gate: h_t (column c) ----------------
        const uint4* a4 = (const uint4*)&zhS[t & 7][0];   // broadcast reads
        float xh_t = h16tof(xhS[p][u * 256 + c]);
        float z_t  = h16tof(zringS[t & 7][c]);
        float s0 = 0.f, s1 = 0.f, s2 = 0.f, s3 = 0.f;
#pragma unroll
        for (int i = 0; i < 32; ++i) {
          uint4 A = a4[i];
          uint4 Wq = W[i];
          s0 = fdot2(uph(A.x), uph(Wq.x), s0);
          s1 = fdot2(uph(A.y), uph(Wq.y), s1);
          s2 = fdot2(uph(A.z), uph(Wq.z), s2);
          s3 = fdot2(uph(A.w), uph(Wq.w), s3);
        }
        float acc = (s0 + s1) + (s2 + s3);
        float htl = tanh_f(acc + xh_t);
        h += z_t * (htl - h);
        histS[t & 7][c] = ftoh16(h);
        if (u < 3) {                      // z_{t+1} already published
          float zn = h16tof(zringS[(t + 1) & 7][c]);
          zhS[(t + 1) & 7][c] = ftoh16(zn * h);
        }
        barrier_lgkm();                   // B_u
        if (u == 3) {                     // B3 published z_{tb+4}; finish zh
          float zn = h16tof(zringS[(t + 1) & 7][c]);
          zhS[(t + 1) & 7][c] = ftoh16(zn * h);
          barrier_lgkm();                 // B4
        }
      } else {
        // ---------------- z gate + all global traffic ----------------
        if (u == 0) {
          int rh = tb + 4 + rr; if (rh > 4095) rh = 4095;
          xhv = *(const uint2*)&xh32[xb32 + (size_t)rh * 128 + (c & 63) * 2];
          int rz = tb + 8 + rr; if (rz > 4095) rz = 4095;
          xzv2 = *(const uint2*)&xz16v[((size_t)b * 4096 + rz) * 256 + c4];
          if (tb > 0) {                   // write back h rows tb-4..tb-1
            int ro = tb - 4 + rr;
            uint2 hv = *(const uint2*)&histS[ro & 7][c4];
            *(uint2*)&hsOut[xb32 + (size_t)ro * 128 + (c & 63) * 2] = hv;
          }
          barrier_lgkm();
        } else if (u == 2) {
          // publish staged xh/xz (vmcnt(N) wait lands here, ~2 steps after
          // issue; keeps the drain + 4 ds_writes off the B3 path)
          *(uint2*)&xhS[p ^ 1][rr * 256 + c4] = xhv;
          *(uint2*)&xzS[p ^ 1][rr * 256 + c4] = xzv2;
          barrier_lgkm();                 // B2
        } else if (u == 3) {
          // MFMA burst: z_{tb+4+r2} = sigmoid(xz + h_{tb-1+r2} @ Uz)
          const int srow = (tb + 7 + (l & 3)) & 7;   // m%4 row select
          const int koff = (l >> 4) * 8;
          float4v acc4[4] = {};
#pragma unroll
          for (int kt = 0; kt < 8; ++kt) {
            half8v a = __builtin_bit_cast(
                half8v, *(const uint4*)&histS[srow][kt * 32 + koff]);
#pragma unroll
            for (int nt = 0; nt < 4; ++nt)
              acc4[nt] = __builtin_amdgcn_mfma_f32_16x16x32_f16(
                  a, __builtin_bit_cast(half8v, W[kt * 4 + nt]), acc4[nt], 0, 0, 0);
          }
          // All 4 lane-quads hold identical C rows (row = reg mod 4):
          // quad q processes time-row q wave-uniformly (4 sigmoids/lane).
          {
            const int q = l >> 4;
            const int lm16 = l & 15;
#pragma unroll
            for (int nt = 0; nt < 4; ++nt) {
              float4v a = acc4[nt];
              float pre = q == 0 ? a[0] : q == 1 ? a[1] : q == 2 ? a[2] : a[3];
              int cn = wv * 64 + nt * 16 + lm16;
              float zv = sigmoid_f(pre + h16tof(xzS[p][q * 256 + cn]));
              zringS[(tb + 4 + q) & 7][cn] = ftoh16(zv);
            }
          }
          barrier_lgkm();                 // B3
          barrier_lgkm();                 // B4
        } else {
          barrier_lgkm();                 // B1
        }
      }
    }
  }

  // tail: write back h rows 4092..4095
  if (g == 1) {
    int ro = 4092 + rr;
    uint2 hv = *(const uint2*)&histS[ro & 7][c4];
    *(uint2*)&hsOut[xb32 + (size_t)ro * 128 + (c & 63) * 2] = hv;
  }
}

// ---------------------------------------------------------------------------
extern "C" void kernel_launch(void* const* d_in, const int* in_sizes, int n_in,
                              void* d_out, int out_size, void* d_ws, size_t ws_size,
                              hipStream_t stream)
{
  (void)in_sizes; (void)n_in; (void)out_size; (void)ws_size;
  const float* x  = (const float*)d_in[0];
  const float* Wz = (const float*)d_in[1];
  const float* Uz = (const float*)d_in[2];
  const float* bz = (const float*)d_in[3];
  const float* Wh = (const float*)d_in[4];
  const float* Uh = (const float*)d_in[5];
  const float* bh = (const float*)d_in[6];
  const float* Wo = (const float*)d_in[7];
  const float* bo = (const float*)d_in[8];

  char* ws = (char*)d_ws;
  _Float16* Wzt  = (_Float16*)(ws);                                   // 64 KB
  _Float16* Wht  = (_Float16*)(ws + (64 << 10));                      // 64 KB
  _Float16* Wot  = (_Float16*)(ws + (128 << 10));                     // 64 KB
  _Float16* xz16 = (_Float16*)(ws + (256 << 10));                     // 64 MB
  _Float16* xh16 = (_Float16*)(ws + (256 << 10) + (size_t)64 * 1024 * 1024); // 64 MB

  _Float16* hs16 = (_Float16*)d_out;  // hs staged in d_out; head GEMM in-place

  prep_transpose<<<dim3(32, 3), 256, 0, stream>>>(Wz, Wh, Wo, Wzt, Wht, Wot);
  gemm_mfma<128, 256, true, true><<<1024, 256, 0, stream>>>(x, Wzt, bz, xz16);
  gemm_mfma<128, 256, true, true><<<1024, 256, 0, stream>>>(x, Wht, bh, xh16);
  scan_kernel<<<32, 512, 0, stream>>>((const u32*)xz16, (const u32*)xh16,
                                      Uz, Uh, (u32*)d_out);
  gemm_mfma<256, 128, false, false><<<1024, 256, 0, stream>>>(hs16, Wot, bo, d_out);
}

// Round 2
// 2741.460 us; speedup vs baseline: 1.2510x; 1.2510x over previous
//
#include <hip/hip_runtime.h>
#include <hip/hip_bf16.h>

typedef _Float16 half2v __attribute__((ext_vector_type(2)));
typedef _Float16 half8v __attribute__((ext_vector_type(8)));
typedef float float4v __attribute__((ext_vector_type(4)));
typedef unsigned int u32;
typedef unsigned short u16;

#define DEV static __device__ __forceinline__

DEV u32 pack2(float a, float b) {
  half2v h = { (_Float16)a, (_Float16)b };
  return __builtin_bit_cast(u32, h);
}
DEV half2v uph(u32 u) { return __builtin_bit_cast(half2v, u); }
DEV u16 ftoh16(float f) { return __builtin_bit_cast(u16, (_Float16)f); }
DEV float h16tof(u16 s) { return (float)__builtin_bit_cast(_Float16, s); }

#if __has_builtin(__builtin_amdgcn_fdot2)
DEV float fdot2(half2v a, half2v b, float c) { return __builtin_amdgcn_fdot2(a, b, c, false); }
#else
DEV float fdot2(half2v a, half2v b, float c) {
  return c + (float)a.x * (float)b.x + (float)a.y * (float)b.y;
}
#endif

DEV float fast_rcp(float x) { return __builtin_amdgcn_rcpf(x); }
DEV float sigmoid_f(float x) { return fast_rcp(1.f + exp2f(-1.4426950408889634f * x)); }
DEV float tanh_f(float x) {
  float e = exp2f(x * 2.8853900817779268f);  // e^(2x)
  return 1.f - 2.f * fast_rcp(e + 1.f);
}

// Raw barrier: LDS-publish only. Deliberately NO vmcnt(0) — in-flight global
// loads/stores keep flying across it (the compiler's own data-dep vmcnt(N)
// drains them right before their LDS write, 2-3 steps after issue).
DEV void barrier_lgkm() {
  __asm__ __volatile__("s_waitcnt lgkmcnt(0)\ns_barrier" ::: "memory");
}

// ---------------------------------------------------------------------------
// Prep: transpose + f16-convert the three weight matrices (dst[c][r] = src[r][c])
// ---------------------------------------------------------------------------
__global__ void prep_transpose(const float* __restrict__ Wz, const float* __restrict__ Wh,
                               const float* __restrict__ Wo, _Float16* __restrict__ Wzt,
                               _Float16* __restrict__ Wht, _Float16* __restrict__ Wot)
{
  const float* src; _Float16* dst; int R, C;
  if (blockIdx.y == 0)      { src = Wz; dst = Wzt; R = 128; C = 256; }
  else if (blockIdx.y == 1) { src = Wh; dst = Wht; R = 128; C = 256; }
  else                      { src = Wo; dst = Wot; R = 256; C = 128; }
  int total = R * C;
  for (int idx = blockIdx.x * blockDim.x + threadIdx.x; idx < total;
       idx += gridDim.x * blockDim.x) {
    int rr = idx / C, cc = idx % C;
    dst[(size_t)cc * R + rr] = (_Float16)src[idx];
  }
}

// ---------------------------------------------------------------------------
// MFMA GEMM: out[M x N] = A[M x K] * Bt^T (+bias). Bt is [N][K] f16 (pre-transposed).
// ---------------------------------------------------------------------------
template <int K, int N, bool A_F32, bool OUT_F16>
__global__ __launch_bounds__(256, 2) void gemm_mfma(
    const void* __restrict__ A_, const _Float16* __restrict__ Bt,
    const float* __restrict__ bias, void* __restrict__ out)
{
  __shared__ _Float16 Blds[N * K];  // 64 KB

  const int tid = threadIdx.x;
  constexpr int CHUNKS = K / 8;
  constexpr int ITER = (N * K / 8) / 256;
#pragma unroll
  for (int i = 0; i < ITER; ++i) {
    int idx = tid + i * 256;
    int n = idx / CHUNKS;
    int c = idx % CHUNKS;
    int cs = c ^ (n & 7);
    *(uint4*)(Blds + (size_t)n * K + cs * 8) =
        *(const uint4*)(Bt + (size_t)n * K + c * 8);
  }
  __syncthreads();

  const int w = tid >> 6, l = tid & 63;
  const int lm = l & 15, lq = l >> 4;
  const size_t m0 = (size_t)blockIdx.x * 128;

  float4v acc[2][N / 16] = {};

#pragma unroll
  for (int kk = 0; kk < K / 32; ++kk) {
    const int kbase = kk * 32 + lq * 8;
    half8v af[2];
#pragma unroll
    for (int ms = 0; ms < 2; ++ms) {
      const size_t row = m0 + (size_t)(w * 2 + ms) * 16 + lm;
      if constexpr (A_F32) {
        const float* ap = (const float*)A_ + row * K + kbase;
        float4 x0 = *(const float4*)ap;
        float4 x1 = *(const float4*)(ap + 4);
        af[ms] = half8v{(_Float16)x0.x, (_Float16)x0.y, (_Float16)x0.z, (_Float16)x0.w,
                        (_Float16)x1.x, (_Float16)x1.y, (_Float16)x1.z, (_Float16)x1.w};
      } else {
        af[ms] = *(const half8v*)((const _Float16*)A_ + row * K + kbase);
      }
    }
    const int c = kk * 4 + lq;
#pragma unroll
    for (int nt = 0; nt < N / 16; ++nt) {
      const int n = nt * 16 + lm;
      half8v bf = *(const half8v*)(Blds + (size_t)n * K + (c ^ (lm & 7)) * 8);
      acc[0][nt] = __builtin_amdgcn_mfma_f32_16x16x32_f16(af[0], bf, acc[0][nt], 0, 0, 0);
      acc[1][nt] = __builtin_amdgcn_mfma_f32_16x16x32_f16(af[1], bf, acc[1][nt], 0, 0, 0);
    }
  }

#pragma unroll
  for (int ms = 0; ms < 2; ++ms) {
    const size_t rowbase = m0 + (size_t)(w * 2 + ms) * 16 + lq * 4;
#pragma unroll
    for (int nt = 0; nt < N / 16; ++nt) {
      const int col = nt * 16 + lm;
      const float bcol = bias[col];
#pragma unroll
      for (int rr = 0; rr < 4; ++rr) {
        const size_t row = rowbase + rr;
        float v = acc[ms][nt][rr] + bcol;
        if constexpr (OUT_F16) ((_Float16*)out)[row * N + col] = (_Float16)v;
        else                   ((float*)out)[row * N + col] = v;
      }
    }
  }
}

// ---------------------------------------------------------------------------
// Sequential scan. One WG (512 thr, 8 waves) per batch element.
//  g0 (waves 0-3): candidate gate via REPLICATED-ROW MFMA mat-vec.
//    Uh is preloaded as B-fragments (same layout as g1's Uz). The zh
//    A-fragment is read with an address depending only on l>>4, so ALL 16
//    A-rows hold the same zh vector -> every lane's C regs replicate the
//    result for col nt*16+(l&15); lane l selects nt=l>>4, recovering its
//    owned column c = wv*64+l. LDS return traffic per wave per step drops
//    32 KB -> 8 KB (8 ds_read_b128 vs 32 broadcast b128) — the LDS pipe was
//    the measured bottleneck (~128 KB/step/CU ~ 1500 cy/step).
//  g1 (waves 4-7): z gate via MFMA once per 4 steps (u==3); all global
//    traffic issued at u==0 into REGISTERS, ds_written to LDS at u==2 so the
//    vmcnt wait lands ~2 steps (~1000cy) after issue and stays off the B3
//    path. Raw lgkm-only barriers keep HBM latency off the barrier path.
//  Barriers: 5 per 4-step group (B0..B3 + mini-barrier B4 that publishes the
//  group-boundary zh after g1's z burst lands).
// ---------------------------------------------------------------------------
__global__ __launch_bounds__(512, 2) void scan_kernel(
    const u32* __restrict__ xz32, const u32* __restrict__ xh32,
    const float* __restrict__ Uz, const float* __restrict__ Uh,
    u32* __restrict__ hsOut)
{
  const int b   = blockIdx.x;
  const int tid = threadIdx.x;
  const int w   = tid >> 6;
  const int l   = tid & 63;
  const int g   = w >> 2;
  const int wv  = w & 3;

  // pitch 264 u16 (=528B): ring slots are 4 banks apart -> the 4-row MFMA
  // A-frag reads hit disjoint bank quads.
  __shared__ __align__(16) u16 histS[8][264];   // h_t, f16, 1 col per u16
  __shared__ __align__(16) u16 zringS[8][264];  // z_t
  __shared__ __align__(16) u16 zhS[8][264];     // z_t * h_{t-1}  (a-vector)
  __shared__ __align__(16) u16 xhS[2][1024];    // xh staging, 4 rows x 256
  __shared__ __align__(16) u16 xzS[2][1024];    // xz staging, 4 rows x 256

  uint4 W[32];  // B-frags: g0 = Uh, g1 = Uz. W[kt*4+nt],
                // B[k=kt*32+(l>>4)*8+j][n=wv*64+nt*16+(l&15)]

  const size_t xb32 = (size_t)b * 4096 * 128;   // u32 units
  const u16* xz16v = (const u16*)xz32;
  const int c   = wv * 64 + l;        // g0: owned column / g1: linear id
  const int rr  = c >> 6;             // staging row 0..3
  const int c4  = (c & 63) * 4;       // staging col (u16), 4 per thread

  {
    const float* U = (g == 0) ? Uh : Uz;
    const int lm = l & 15, lo = (l >> 4) * 8;
#pragma unroll
    for (int kt = 0; kt < 8; ++kt)
#pragma unroll
      for (int nt = 0; nt < 4; ++nt) {
        u32 q[4];
#pragma unroll
        for (int p2 = 0; p2 < 4; ++p2) {
          int k0 = kt * 32 + lo + 2 * p2;
          int cn = wv * 64 + nt * 16 + lm;
          q[p2] = pack2(U[(size_t)k0 * 256 + cn], U[(size_t)(k0 + 1) * 256 + cn]);
        }
        W[kt * 4 + nt] = make_uint4(q[0], q[1], q[2], q[3]);
      }
  }

  // zero h_{-4..-1} (slots 4..7) and zh_0 (= z_0 * h_{-1} = 0)
  for (int i = tid; i < 4 * 264; i += 512) (&histS[4][0])[i] = 0;
  for (int i = tid; i < 264; i += 512) zhS[0][i] = 0;

  if (g == 1) {
    // z_0..3 = sigmoid(xz rows 0..3);  stage xh rows 0..3, xz rows 4..7
    uint2 xzv = *(const uint2*)&xz16v[((size_t)b * 4096 + rr) * 256 + c4];
    half2v a0 = uph(xzv.x), a1 = uph(xzv.y);
    u32 z01 = pack2(sigmoid_f((float)a0.x), sigmoid_f((float)a0.y));
    u32 z23 = pack2(sigmoid_f((float)a1.x), sigmoid_f((float)a1.y));
    *(uint2*)&zringS[rr][c4] = make_uint2(z01, z23);
    *(uint2*)&xhS[0][rr * 256 + c4] =
        *(const uint2*)&xh32[xb32 + (size_t)rr * 128 + (c & 63) * 2];
    *(uint2*)&xzS[0][rr * 256 + c4] =
        *(const uint2*)&xz16v[((size_t)b * 4096 + 4 + rr) * 256 + c4];
  }
  float h = 0.f;
  __syncthreads();

  const int koff = (l >> 4) * 8;   // A-frag k-slice (depends only on lq)
  const int q    = l >> 4;

  for (int tb = 0; tb < 4096; tb += 4) {
    const int p = (tb >> 2) & 1;
    uint2 xhv, xzv2;                      // g1: staged in regs u0 -> u2
#pragma unroll
    for (int u = 0; u < 4; ++u) {
      const int t = tb + u;
      if (g == 0) {
        // ---------------- candidate gate: h_t (column c) ----------------
        // Replicated-row MFMA mat-vec: acc4[nt] row-replicated result.
        const u16* zrow = &zhS[t & 7][0];
        float xh_t = h16tof(xhS[p][u * 256 + c]);
        float z_t  = h16tof(zringS[t & 7][c]);
        float4v acc4[4] = {};
#pragma unroll
        for (int kt = 0; kt < 8; ++kt) {
          half8v a = __builtin_bit_cast(
              half8v, *(const uint4*)&zrow[kt * 32 + koff]);
#pragma unroll
          for (int nt = 0; nt < 4; ++nt)
            acc4[nt] = __builtin_amdgcn_mfma_f32_16x16x32_f16(
                a, __builtin_bit_cast(half8v, W[kt * 4 + nt]), acc4[nt], 0, 0, 0);
        }
        // All rows replicate zh -> every reg of acc4[nt] holds the result
        // for col nt*16+(l&15). Lane l wants nt == l>>4 (col == c).
        float pre = q == 0 ? acc4[0][0] : q == 1 ? acc4[1][0]
                  : q == 2 ? acc4[2][0] : acc4[3][0];
        float htl = tanh_f(pre + xh_t);
        h += z_t * (htl - h);
        histS[t & 7][c] = ftoh16(h);
        if (u < 3) {                      // z_{t+1} already published
          float zn = h16tof(zringS[(t + 1) & 7][c]);
          zhS[(t + 1) & 7][c] = ftoh16(zn * h);
        }
        barrier_lgkm();                   // B_u
        if (u == 3) {                     // B3 published z_{tb+4}; finish zh
          float zn = h16tof(zringS[(t + 1) & 7][c]);
          zhS[(t + 1) & 7][c] = ftoh16(zn * h);
          barrier_lgkm();                 // B4
        }
      } else {
        // ---------------- z gate + all global traffic ----------------
        if (u == 0) {
          int rh = tb + 4 + rr; if (rh > 4095) rh = 4095;
          xhv = *(const uint2*)&xh32[xb32 + (size_t)rh * 128 + (c & 63) * 2];
          int rz = tb + 8 + rr; if (rz > 4095) rz = 4095;
          xzv2 = *(const uint2*)&xz16v[((size_t)b * 4096 + rz) * 256 + c4];
          if (tb > 0) {                   // write back h rows tb-4..tb-1
            int ro = tb - 4 + rr;
            uint2 hv = *(const uint2*)&histS[ro & 7][c4];
            *(uint2*)&hsOut[xb32 + (size_t)ro * 128 + (c & 63) * 2] = hv;
          }
          barrier_lgkm();
        } else if (u == 2) {
          // publish staged xh/xz (vmcnt(N) wait lands here, ~2 steps after
          // issue; keeps the drain + 4 ds_writes off the B3 path)
          *(uint2*)&xhS[p ^ 1][rr * 256 + c4] = xhv;
          *(uint2*)&xzS[p ^ 1][rr * 256 + c4] = xzv2;
          barrier_lgkm();                 // B2
        } else if (u == 3) {
          // MFMA burst: z_{tb+4+r2} = sigmoid(xz + h_{tb-1+r2} @ Uz)
          const int srow = (tb + 7 + (l & 3)) & 7;   // m%4 row select
          float4v acc4[4] = {};
#pragma unroll
          for (int kt = 0; kt < 8; ++kt) {
            half8v a = __builtin_bit_cast(
                half8v, *(const uint4*)&histS[srow][kt * 32 + koff]);
#pragma unroll
            for (int nt = 0; nt < 4; ++nt)
              acc4[nt] = __builtin_amdgcn_mfma_f32_16x16x32_f16(
                  a, __builtin_bit_cast(half8v, W[kt * 4 + nt]), acc4[nt], 0, 0, 0);
          }
          // All 4 lane-quads hold identical C rows (row = reg mod 4):
          // quad q processes time-row q wave-uniformly (4 sigmoids/lane).
          {
            const int lm16 = l & 15;
#pragma unroll
            for (int nt = 0; nt < 4; ++nt) {
              float4v a = acc4[nt];
              float pre = q == 0 ? a[0] : q == 1 ? a[1] : q == 2 ? a[2] : a[3];
              int cn = wv * 64 + nt * 16 + lm16;
              float zv = sigmoid_f(pre + h16tof(xzS[p][q * 256 + cn]));
              zringS[(tb + 4 + q) & 7][cn] = ftoh16(zv);
            }
          }
          barrier_lgkm();                 // B3
          barrier_lgkm();                 // B4
        } else {
          barrier_lgkm();                 // B1
        }
      }
    }
  }

  // tail: write back h rows 4092..4095
  if (g == 1) {
    int ro = 4092 + rr;
    uint2 hv = *(const uint2*)&histS[ro & 7][c4];
    *(uint2*)&hsOut[xb32 + (size_t)ro * 128 + (c & 63) * 2] = hv;
  }
}

// ---------------------------------------------------------------------------
extern "C" void kernel_launch(void* const* d_in, const int* in_sizes, int n_in,
                              void* d_out, int out_size, void* d_ws, size_t ws_size,
                              hipStream_t stream)
{
  (void)in_sizes; (void)n_in; (void)out_size; (void)ws_size;
  const float* x  = (const float*)d_in[0];
  const float* Wz = (const float*)d_in[1];
  const float* Uz = (const float*)d_in[2];
  const float* bz = (const float*)d_in[3];
  const float* Wh = (const float*)d_in[4];
  const float* Uh = (const float*)d_in[5];
  const float* bh = (const float*)d_in[6];
  const float* Wo = (const float*)d_in[7];
  const float* bo = (const float*)d_in[8];

  char* ws = (char*)d_ws;
  _Float16* Wzt  = (_Float16*)(ws);                                   // 64 KB
  _Float16* Wht  = (_Float16*)(ws + (64 << 10));                      // 64 KB
  _Float16* Wot  = (_Float16*)(ws + (128 << 10));                     // 64 KB
  _Float16* xz16 = (_Float16*)(ws + (256 << 10));                     // 64 MB
  _Float16* xh16 = (_Float16*)(ws + (256 << 10) + (size_t)64 * 1024 * 1024); // 64 MB

  _Float16* hs16 = (_Float16*)d_out;  // hs staged in d_out; head GEMM in-place

  prep_transpose<<<dim3(32, 3), 256, 0, stream>>>(Wz, Wh, Wo, Wzt, Wht, Wot);
  gemm_mfma<128, 256, true, true><<<1024, 256, 0, stream>>>(x, Wzt, bz, xz16);
  gemm_mfma<128, 256, true, true><<<1024, 256, 0, stream>>>(x, Wht, bh, xh16);
  scan_kernel<<<32, 512, 0, stream>>>((const u32*)xz16, (const u32*)xh16,
                                      Uz, Uh, (u32*)d_out);
  gemm_mfma<256, 128, false, false><<<1024, 256, 0, stream>>>(hs16, Wot, bo, d_out);
}